// Round 2
// baseline (5908.194 us; speedup 1.0000x reference)
//
#include <hip/hip_runtime.h>
#include <hip/hip_bf16.h>

// PointDSC-like network. B=2, N=3000, C=128, H=1, L=6.
// Round 2: all I/O is FP32 (reference dtypes are jnp.float32; the test label's
// "bf16" is hard-coded text). fp32 VALU compute, correctness-first.
// ws usage: 5 FEAT buffers + 256 floats = 15.4 MB.

#define BB 2
#define NN 3000
#define CC 128
#define LAYERS 6
#define BN_EPS 1e-5f
#define ATT_SCALE 0.08838834764831845f  // 1/sqrt(128)

// ---------------- init embedding: x[b,c,n] = sum_d W[c,d]*corr[b,n,d] + b[c]
__global__ void init_conv(const float* __restrict__ corr, const float* __restrict__ W,
                          const float* __restrict__ bias, float* __restrict__ x) {
  int idx = blockIdx.x * 256 + threadIdx.x;
  if (idx >= BB * CC * NN) return;
  int n = idx % NN;
  int c = (idx / NN) % CC;
  int b = idx / (NN * CC);
  const float* cp = corr + (b * NN + n) * 6;
  float acc = bias[c];
#pragma unroll
  for (int d = 0; d < 6; ++d) acc += W[c * 6 + d] * cp[d];
  x[idx] = acc;
}

// ---------------- generic pointwise conv: out[b,co,n] = sum_ci W[co,ci]*in[b,ci,n] + bias[co]
// MODE: 0 = plain, 1 = relu, 2 = residual add (out = res + conv)
// block: 256 threads, tile of 32 flattened points (p = b*N+n), all COUT channels.
// W staged in LDS in ci-chunks of CH (fp32 weights are too big for one shot at 128x128).
template <int CIN, int COUT, int MODE>
__launch_bounds__(256)
__global__ void conv_k(const float* __restrict__ in, float* __restrict__ out,
                       const float* __restrict__ W, const float* __restrict__ bias,
                       const float* __restrict__ res) {
  constexpr int CH = (CIN > 64) ? 64 : CIN;
  __shared__ alignas(16) float Xs[CIN][32];
  __shared__ float Ws[COUT][CH + 1];
  const int tid = threadIdx.x;
  const int p0 = blockIdx.x * 32;

  for (int idx = tid; idx < CIN * 32; idx += 256) {
    int ci = idx / 32, j = idx % 32;
    int p = p0 + j;
    float v = 0.f;
    if (p < BB * NN) {
      int b = p / NN, n = p % NN;
      v = in[(b * CIN + ci) * NN + n];
    }
    Xs[ci][j] = v;
  }

  constexpr int KPT = COUT / 32;  // channels per thread
  const int nb = (tid % 8) * 4;   // 4 points
  const int cb = (tid / 8) * KPT;

  float acc[KPT][4];
#pragma unroll
  for (int k = 0; k < KPT; ++k)
#pragma unroll
    for (int j = 0; j < 4; ++j) acc[k][j] = 0.f;

  for (int c0 = 0; c0 < CIN; c0 += CH) {
    __syncthreads();  // Xs staged / previous Ws chunk consumed
    for (int idx = tid; idx < COUT * CH; idx += 256) {
      int co = idx / CH, cc = idx % CH;
      Ws[co][cc] = W[co * CIN + c0 + cc];
    }
    __syncthreads();
#pragma unroll 4
    for (int cc = 0; cc < CH; ++cc) {
      float4 xv = *reinterpret_cast<const float4*>(&Xs[c0 + cc][nb]);
#pragma unroll
      for (int k = 0; k < KPT; ++k) {
        float w = Ws[cb + k][cc];
        acc[k][0] += w * xv.x;
        acc[k][1] += w * xv.y;
        acc[k][2] += w * xv.z;
        acc[k][3] += w * xv.w;
      }
    }
  }

#pragma unroll
  for (int k = 0; k < KPT; ++k) {
    float bv = bias[cb + k];
#pragma unroll
    for (int j = 0; j < 4; ++j) {
      int p = p0 + nb + j;
      if (p < BB * NN) {
        int b = p / NN, n = p % NN;
        int o = (b * COUT + cb + k) * NN + n;
        float v = acc[k][j] + bv;
        if (MODE == 1) v = v > 0.f ? v : 0.f;
        if (MODE == 2) v += res[o];
        out[o] = v;
      }
    }
  }
}

// ---------------- BN batch stats (training mode): per-channel scale/shift
template <int COUT>
__launch_bounds__(256)
__global__ void bn_stats(const float* __restrict__ y, const float* __restrict__ g,
                         const float* __restrict__ beta, float* __restrict__ ss) {
  int c = blockIdx.x;
  float s = 0.f, s2 = 0.f;
  for (int b = 0; b < BB; ++b) {
    const float* row = y + (b * COUT + c) * NN;
    for (int n = threadIdx.x; n < NN; n += 256) {
      float v = row[n];
      s += v;
      s2 += v * v;
    }
  }
  for (int off = 32; off > 0; off >>= 1) {
    s += __shfl_down(s, off);
    s2 += __shfl_down(s2, off);
  }
  __shared__ float rs[4], rs2[4];
  int wid = threadIdx.x >> 6, lane = threadIdx.x & 63;
  if (lane == 0) {
    rs[wid] = s;
    rs2[wid] = s2;
  }
  __syncthreads();
  if (threadIdx.x == 0) {
    float S = 0.f, S2 = 0.f;
    for (int w = 0; w < 4; ++w) {
      S += rs[w];
      S2 += rs2[w];
    }
    const float inv_cnt = 1.f / (float)(BB * NN);
    float mean = S * inv_cnt;
    float var = S2 * inv_cnt - mean * mean;
    float scale = g[c] * rsqrtf(var + BN_EPS);
    ss[c] = scale;
    ss[COUT + c] = beta[c] - mean * scale;
  }
}

template <int COUT>
__global__ void bn_apply(const float* __restrict__ y, const float* __restrict__ ss,
                         float* __restrict__ out) {
  int idx = blockIdx.x * 256 + threadIdx.x;
  if (idx >= BB * COUT * NN) return;
  int c = (idx / NN) % COUT;
  float v = y[idx] * ss[c] + ss[COUT + c];
  out[idx] = v > 0.f ? v : 0.f;
}

// ---------------- attention with spatial-compatibility gating (flash-style)
// logit[o,i] = max(0, 1-(||s_o-s_i||-||t_o-t_i||)^2) * SCALE * (Q[:,o].K[:,i])
// msg[c,o] = sum_i softmax_i(logit)[o,i] * V[c,i]
__launch_bounds__(256)
__global__ void attn_k(const float* __restrict__ Qg, const float* __restrict__ Kg,
                       const float* __restrict__ Vg, const float* __restrict__ srcp,
                       const float* __restrict__ tgtp, float* __restrict__ msg) {
  const int b = blockIdx.y;
  const int n0 = blockIdx.x * 16;
  const int tid = threadIdx.x;

  __shared__ alignas(16) float Qs[16][132], Ks[16][132], Vs[16][132];
  __shared__ float S[16][17];
  __shared__ float qp[16][6], kp[16][6];

  for (int idx = tid; idx < 2048; idx += 256) {
    int c = idx >> 4, o = idx & 15;
    int n = n0 + o;
    Qs[o][c] = (n < NN) ? Qg[(b * CC + c) * NN + n] : 0.f;
  }
  if (tid < 96) {
    int o = tid / 6, d = tid % 6;
    int n = n0 + o;
    float v = 0.f;
    if (n < NN) v = (d < 3) ? srcp[(b * NN + n) * 3 + d] : tgtp[(b * NN + n) * 3 + d - 3];
    qp[o][d] = v;
  }

  const int o_s = tid >> 4, i_s = tid & 15;  // score-phase role
  const int o_a = tid & 15, g = tid >> 4;    // accum-phase role: 8 channels each
  float m = -1e30f, l = 0.f;
  float acc[8];
#pragma unroll
  for (int k = 0; k < 8; ++k) acc[k] = 0.f;

  const int KT = (NN + 15) / 16;
  for (int kt = 0; kt < KT; ++kt) {
    const int i0 = kt * 16;
    __syncthreads();  // prev accum done before restaging
    for (int idx = tid; idx < 2048; idx += 256) {
      int c = idx >> 4, i = idx & 15;
      int n = i0 + i;
      float kv = 0.f, vv = 0.f;
      if (n < NN) {
        kv = Kg[(b * CC + c) * NN + n];
        vv = Vg[(b * CC + c) * NN + n];
      }
      Ks[i][c] = kv;
      Vs[i][c] = vv;
    }
    if (tid < 96) {
      int i = tid / 6, d = tid % 6;
      int n = i0 + i;
      float v = 0.f;
      if (n < NN) v = (d < 3) ? srcp[(b * NN + n) * 3 + d] : tgtp[(b * NN + n) * 3 + d - 3];
      kp[i][d] = v;
    }
    __syncthreads();

    // ---- scores: one (o,i) pair per thread
    float dot = 0.f;
#pragma unroll
    for (int c4 = 0; c4 < 32; ++c4) {
      float4 q = *reinterpret_cast<const float4*>(&Qs[o_s][c4 * 4]);
      float4 k = *reinterpret_cast<const float4*>(&Ks[i_s][c4 * 4]);
      dot += q.x * k.x + q.y * k.y + q.z * k.z + q.w * k.w;
    }
    float dx = qp[o_s][0] - kp[i_s][0];
    float dy = qp[o_s][1] - kp[i_s][1];
    float dz = qp[o_s][2] - kp[i_s][2];
    float dsrc = sqrtf(dx * dx + dy * dy + dz * dz);
    dx = qp[o_s][3] - kp[i_s][3];
    dy = qp[o_s][4] - kp[i_s][4];
    dz = qp[o_s][5] - kp[i_s][5];
    float dtgt = sqrtf(dx * dx + dy * dy + dz * dz);
    float diff = dsrc - dtgt;
    float scv = 1.f - diff * diff;
    scv = scv > 0.f ? scv : 0.f;
    float logit = scv * ATT_SCALE * dot;
    if (i0 + i_s >= NN) logit = -1e30f;
    S[o_s][i_s] = logit;
    __syncthreads();

    // ---- online softmax + PV accumulate
    float tm = m;
#pragma unroll
    for (int i = 0; i < 16; ++i) tm = fmaxf(tm, S[o_a][i]);
    float alpha = __expf(m - tm);
    float p[16];
    float ps = 0.f;
#pragma unroll
    for (int i = 0; i < 16; ++i) {
      p[i] = __expf(S[o_a][i] - tm);
      ps += p[i];
    }
    l = l * alpha + ps;
    m = tm;
#pragma unroll
    for (int k = 0; k < 8; ++k) acc[k] *= alpha;
#pragma unroll
    for (int i = 0; i < 16; ++i) {
      float pv = p[i];
      float4 v0 = *reinterpret_cast<const float4*>(&Vs[i][g * 8]);
      float4 v1 = *reinterpret_cast<const float4*>(&Vs[i][g * 8 + 4]);
      acc[0] += pv * v0.x;
      acc[1] += pv * v0.y;
      acc[2] += pv * v0.z;
      acc[3] += pv * v0.w;
      acc[4] += pv * v1.x;
      acc[5] += pv * v1.y;
      acc[6] += pv * v1.z;
      acc[7] += pv * v1.w;
    }
  }

  if (n0 + o_a < NN) {
    float inv = 1.f / l;
#pragma unroll
    for (int k = 0; k < 8; ++k)
      msg[(b * CC + g * 8 + k) * NN + n0 + o_a] = acc[k] * inv;
  }
}

// ---------------- head: conf[b,n] = c3b + sum_k c3W[k]*h2[b,k,n]
__global__ void head_c3(const float* __restrict__ h, const float* __restrict__ W,
                        const float* __restrict__ bias, float* __restrict__ out) {
  int p = blockIdx.x * 256 + threadIdx.x;
  if (p >= BB * NN) return;
  int b = p / NN, n = p % NN;
  float acc = bias[0];
#pragma unroll
  for (int k = 0; k < 32; ++k) acc += W[k] * h[(b * 32 + k) * NN + n];
  out[p] = acc;
}

// ---------------- L2-normalize corr_feat over channels
__global__ void norm_out(const float* __restrict__ x, float* __restrict__ out) {
  int p = blockIdx.x * 256 + threadIdx.x;
  if (p >= BB * NN) return;
  int b = p / NN, n = p % NN;
  float ss = 0.f;
  for (int c = 0; c < CC; ++c) {
    float v = x[(b * CC + c) * NN + n];
    ss += v * v;
  }
  float nrm = sqrtf(ss);
  nrm = nrm > 1e-12f ? nrm : 1e-12f;
  float inv = 1.f / nrm;
  for (int c = 0; c < CC; ++c) {
    float v = x[(b * CC + c) * NN + n];
    out[BB * NN + (b * CC + c) * NN + n] = v * inv;
  }
}

extern "C" void kernel_launch(void* const* d_in, const int* in_sizes, int n_in,
                              void* d_out, int out_size, void* d_ws, size_t ws_size,
                              hipStream_t stream) {
  const float* corr = (const float*)d_in[0];
  const float* srcp = (const float*)d_in[1];
  const float* tgtp = (const float*)d_in[2];
  const float* initW = (const float*)d_in[3];
  const float* initb = (const float*)d_in[4];
  const float* pcnW = (const float*)d_in[5];
  const float* pcnb = (const float*)d_in[6];
  const float* pcng = (const float*)d_in[7];
  const float* pcnbeta = (const float*)d_in[8];
  const float* qW = (const float*)d_in[9];
  const float* qb = (const float*)d_in[10];
  const float* kW = (const float*)d_in[11];
  const float* kb = (const float*)d_in[12];
  const float* vW = (const float*)d_in[13];
  const float* vb = (const float*)d_in[14];
  const float* m1W = (const float*)d_in[15];
  const float* m1b = (const float*)d_in[16];
  const float* m1g = (const float*)d_in[17];
  const float* m1beta = (const float*)d_in[18];
  const float* m2W = (const float*)d_in[19];
  const float* m2b = (const float*)d_in[20];
  const float* m2g = (const float*)d_in[21];
  const float* m2beta = (const float*)d_in[22];
  const float* m3W = (const float*)d_in[23];
  const float* m3b = (const float*)d_in[24];
  const float* c1W = (const float*)d_in[25];
  const float* c1b = (const float*)d_in[26];
  const float* c2W = (const float*)d_in[27];
  const float* c2b = (const float*)d_in[28];
  const float* c3W = (const float*)d_in[29];
  const float* c3b = (const float*)d_in[30];

  const int FEAT = BB * CC * NN;  // 768000
  float* ws = (float*)d_ws;
  float* X = ws;            // persistent features
  float* Y = X + FEAT;      // conv temp; aliased as MSG after attention
  float* Qb_ = Y + FEAT;    // Q; aliased as T1 (half used)
  float* Kb_ = Qb_ + FEAT;  // K; aliased as T2 (half used)
  float* Vb_ = Kb_ + FEAT;  // V
  float* SS = Vb_ + FEAT;   // 256 floats of BN scale/shift
  float* MSG = Y;
  float* T1 = Qb_;
  float* T2 = Kb_;

  dim3 blk(256);
  const int PT = (BB * NN + 31) / 32;  // 188 point tiles
  const int G_FEAT = (FEAT + 255) / 256;
  const int G_HALF = (BB * 64 * NN + 255) / 256;
  const int G_PTS = (BB * NN + 255) / 256;

  init_conv<<<G_FEAT, blk, 0, stream>>>(corr, initW, initb, X);

  for (int i = 0; i < LAYERS; ++i) {
    // PointCN: x = relu(bn(conv(x)))
    conv_k<128, 128, 0><<<PT, blk, 0, stream>>>(X, Y, pcnW + i * 128 * 128, pcnb + i * 128, nullptr);
    bn_stats<128><<<128, blk, 0, stream>>>(Y, pcng + i * 128, pcnbeta + i * 128, SS);
    bn_apply<128><<<G_FEAT, blk, 0, stream>>>(Y, SS, X);
    // QKV
    conv_k<128, 128, 0><<<PT, blk, 0, stream>>>(X, Qb_, qW + i * 16384, qb + i * 128, nullptr);
    conv_k<128, 128, 0><<<PT, blk, 0, stream>>>(X, Kb_, kW + i * 16384, kb + i * 128, nullptr);
    conv_k<128, 128, 0><<<PT, blk, 0, stream>>>(X, Vb_, vW + i * 16384, vb + i * 128, nullptr);
    // attention with sc gating -> MSG (aliases Y, which is dead here)
    attn_k<<<dim3((NN + 15) / 16, BB), blk, 0, stream>>>(Qb_, Kb_, Vb_, srcp, tgtp, MSG);
    // bottleneck MLP + residual (T1 aliases Q, T2 aliases K — both dead)
    conv_k<128, 64, 0><<<PT, blk, 0, stream>>>(MSG, T1, m1W + i * 64 * 128, m1b + i * 64, nullptr);
    bn_stats<64><<<64, blk, 0, stream>>>(T1, m1g + i * 64, m1beta + i * 64, SS);
    bn_apply<64><<<G_HALF, blk, 0, stream>>>(T1, SS, T1);
    conv_k<64, 64, 0><<<PT, blk, 0, stream>>>(T1, T2, m2W + i * 64 * 64, m2b + i * 64, nullptr);
    bn_stats<64><<<64, blk, 0, stream>>>(T2, m2g + i * 64, m2beta + i * 64, SS);
    bn_apply<64><<<G_HALF, blk, 0, stream>>>(T2, SS, T2);
    conv_k<64, 128, 2><<<PT, blk, 0, stream>>>(T2, X, m3W + i * 128 * 64, m3b + i * 128, X);
  }

  // head
  conv_k<128, 32, 1><<<PT, blk, 0, stream>>>(X, T1, c1W, c1b, nullptr);
  conv_k<32, 32, 1><<<PT, blk, 0, stream>>>(T1, T2, c2W, c2b, nullptr);
  head_c3<<<G_PTS, blk, 0, stream>>>(T2, c3W, c3b, (float*)d_out);
  norm_out<<<G_PTS, blk, 0, stream>>>(X, (float*)d_out);
}